// Round 13
// baseline (33.240 us; speedup 1.0000x reference)
//
#include <hip/hip_runtime.h>

#define NN 1024

typedef __attribute__((ext_vector_type(8))) short short8;
typedef __attribute__((ext_vector_type(4))) float floatx4;

// ---- ws layout (bytes) ----
#define RF_OFF   0u          // f32 Rf[256][1024]: R~[h][i] = |w2_h|*(z_i.W1row_h + b1_h)   1 MiB
#define CF_OFF   1048576u    // f32 Cf[32][1024][8]: Cn[hpg][j][e] = -|w2|*(z_j.W1col)      1 MiB

__device__ __forceinline__ unsigned short f2bf(float x) {  // RNE f32->bf16
  unsigned u = __float_as_uint(x);
  return (unsigned short)((u + 0x7FFFu + ((u >> 16) & 1u)) >> 16);
}

// ---------------- k1: fused prep + fc1 GEMM (bf16 MFMA) -> f32 Rf / Cf ----------------
// Staging + MFMA core byte-identical to r11 (proven). Epilogue writes f32:
//   R-half (q0<256): Rf[q][i]  (transposed via LDS tile)
//   C-half:          Cf[hpg][j][8]  (8 h-values contiguous per column j)
__global__ __launch_bounds__(256) void k1_fused(const float* __restrict__ z,
    const float* __restrict__ W1, const float* __restrict__ b1,
    const float* __restrict__ W2, char* __restrict__ ws) {
  __shared__ unsigned short zsh[16][272];      // 8.7 KB
  __shared__ unsigned short wsh[4][16][272];   // 34.8 KB
  __shared__ float tile[4][16][17];            // 4.4 KB
  float* Rf = (float*)(ws + RF_OFF);
  float* Cf = (float*)(ws + CF_OFF);

  const int t = threadIdx.x;
  const int l = t & 63, w = t >> 6;
  const int i0 = blockIdx.x * 16;
  const int tid = blockIdx.y * 4 + w;          // q-tile id 0..31
  const int q0 = tid * 16;                     // 0..496
  const bool topR = q0 < 256;
  const int h0 = q0 & 255;
  const int off = topR ? 0 : 256;

  // stage z i-tile: 1024 float4, 4 per thread, coalesced; convert to bf16
  #pragma unroll
  for (int k = 0; k < 4; ++k) {
    const int f = t + k * 256;                 // float4 index 0..1023
    const int r = f >> 6, c4 = f & 63;
    const float4 v = *(const float4*)(z + (i0 + r) * 256 + c4 * 4);
    ushort4 u;
    u.x = f2bf(v.x); u.y = f2bf(v.y); u.z = f2bf(v.z); u.w = f2bf(v.w);
    *(ushort4*)&zsh[r][c4 * 4] = u;
  }
  // stage W1 q-slice (per wave): row r, lane l reads float4 #l of the 256-f32 row
  #pragma unroll 4
  for (int r = 0; r < 16; ++r) {
    const int h = h0 + r;
    const float wa = fabsf(W2[h]);             // wave-uniform -> scalar
    const float sc = topR ? wa : -wa;          // C-half carries the negation
    const float4 v = *(const float4*)(W1 + h * 512 + off + l * 4);
    ushort4 u;
    u.x = f2bf(v.x * sc); u.y = f2bf(v.y * sc);
    u.z = f2bf(v.z * sc); u.w = f2bf(v.w * sc);
    *(ushort4*)&wsh[w][r][l * 4] = u;
  }
  __syncthreads();

  // MFMA: A = zsh rows (i), B = wsh rows (q)
  floatx4 acc = {0.f, 0.f, 0.f, 0.f};
  const int fr = l & 15, fg = (l >> 4) * 8;
  #pragma unroll
  for (int kk = 0; kk < 8; ++kk) {
    const short8 a  = *(const short8*)&zsh[fr][fg + kk * 32];
    const short8 bb = *(const short8*)&wsh[w][fr][fg + kk * 32];
    acc = __builtin_amdgcn_mfma_f32_16x16x32_bf16(a, bb, acc, 0, 0, 0);
  }

  const int col = l & 15, r0 = (l >> 4) * 4;   // D: col=lane&15, row=(lane>>4)*4+reg
  float bias = 0.f;
  if (topR) {                                  // R-half: fold |w2|*b1
    const int h = q0 + col;
    bias = b1[h] * fabsf(W2[h]);
  }
  #pragma unroll
  for (int q = 0; q < 4; ++q) tile[w][r0 + q][col] = acc[q] + bias;
  __syncthreads();
  const int il = l & 15, g2 = l >> 4;          // g2 in 0..3
  if (topR) {
    // Rf[q0+qc][i0+il], qc = g2*4..g2*4+3; 16-lane coalesced per store
    #pragma unroll
    for (int e = 0; e < 4; ++e) {
      const int qc = g2 * 4 + e;
      Rf[(q0 + qc) * 1024 + i0 + il] = tile[w][il][qc];
    }
  } else {
    const int hpg = ((q0 - 256) >> 3) + (g2 >> 1);
    float4 v;
    v.x = tile[w][il][g2 * 4 + 0]; v.y = tile[w][il][g2 * 4 + 1];
    v.z = tile[w][il][g2 * 4 + 2]; v.w = tile[w][il][g2 * 4 + 3];
    *(float4*)(Cf + (hpg * 1024 + (i0 + il)) * 8 + (g2 & 1) * 4) = v;
  }
}

// ---------------- k2: pairwise decode, f32 core (guaranteed 2-cyc VALU) ----------------
// r11 structure at i-tile 16: grid (64,16)=1024 blocks (4/CU), 256 thr = 4 waves
// (4 waves/SIMD). Wave w owns hpgs [8w,8w+8) = 64 h for all 16 i x 64 j.
// Lane (li,lj): rows li*4.., cols lj+16*jj. Rl staged once (16 KB); C 8-f32 per
// hpg per jj coalesced; sign from static-indexed reg array. part[] combine as r11.
// Inner: per h: 4 kv-fma + 16 x (v_max_f32 + v_fmac_f32) = 36 VALU, model 7.7 us.
__global__ __launch_bounds__(256) void k2_pair(const float* __restrict__ Rf,
    const float* __restrict__ Cf, const float* __restrict__ W2,
    const float* __restrict__ b2v, float* __restrict__ out) {
  __shared__ float Rl[256][16];            // 16 KiB
  __shared__ float part[4][16][65];        // 16.6 KiB
  __shared__ float partkv[4][64];          // 1 KiB
  __shared__ float MulS[256];              // 1 KiB
  const int t = threadIdx.x;
  const int lane = t & 63, w = t >> 6;
  const int li = lane >> 4, lj = lane & 15;
  const int i0 = blockIdx.x * 16, j0 = blockIdx.y * 64;

  MulS[t] = (W2[t] > 0.f) ? 1.f : -1.f;
  // stage Rl[h][0..15] = Rf[h][i0..i0+15]: 1024 float4, 4/thread, coalesced
  #pragma unroll
  for (int k = 0; k < 4; ++k) {
    const int f = t + k * 256;               // float4 index
    const int h = f >> 2, c4 = f & 3;
    *(float4*)&Rl[h][c4 * 4] = *(const float4*)(Rf + h * 1024 + i0 + c4 * 4);
  }
  __syncthreads();

  const int hbase = w * 8;                   // hpg range [8w, 8w+8)
  float acc[4][4] = {};
  float kv[4] = {};

  #pragma unroll 2
  for (int g = 0; g < 8; ++g) {
    const int hpg = hbase + g;
    // C: 8 f32 per jj (2 float4), coalesced per 16-lane group
    float carr[4][8];
    #pragma unroll
    for (int jj = 0; jj < 4; ++jj) {
      const float* cp = Cf + (hpg * 1024 + j0 + lj + 16 * jj) * 8;
      *(float4*)&carr[jj][0] = *(const float4*)cp;
      *(float4*)&carr[jj][4] = *(const float4*)(cp + 4);
    }
    float sarr[8];
    *(float4*)&sarr[0] = *(const float4*)&MulS[hpg * 8];
    *(float4*)&sarr[4] = *(const float4*)&MulS[hpg * 8 + 4];

    #pragma unroll
    for (int e = 0; e < 8; ++e) {
      const int h = hpg * 8 + e;
      const float4 ra = *(const float4*)&Rl[h][li * 4];
      const float sh = sarr[e];
      #pragma unroll
      for (int jj = 0; jj < 4; ++jj) {
        const float c = carr[jj][e];
        kv[jj] = fmaf(sh, c, kv[jj]);
        acc[0][jj] = fmaf(fmaxf(ra.x, c), sh, acc[0][jj]);
        acc[1][jj] = fmaf(fmaxf(ra.y, c), sh, acc[1][jj]);
        acc[2][jj] = fmaf(fmaxf(ra.z, c), sh, acc[2][jj]);
        acc[3][jj] = fmaf(fmaxf(ra.w, c), sh, acc[3][jj]);
      }
    }
  }

  #pragma unroll
  for (int ii = 0; ii < 4; ++ii)
    #pragma unroll
    for (int jj = 0; jj < 4; ++jj)
      part[w][li * 4 + ii][lj + 16 * jj] = acc[ii][jj];
  if (li == 0) {
    #pragma unroll
    for (int jj = 0; jj < 4; ++jj) partkv[w][lj + 16 * jj] = kv[jj];
  }
  __syncthreads();

  // combine + sigmoid: 256 threads x 4 outputs
  const int jl = t & 63, ib = (t >> 6) * 4;
  const float kvt = partkv[0][jl] + partkv[1][jl] + partkv[2][jl] + partkv[3][jl];
  const float base = b2v[0] - kvt;           // Kv[j] = b2 - sum_h s*Cn
  #pragma unroll
  for (int u = 0; u < 4; ++u) {
    const int il = ib + u;
    const float x = part[0][il][jl] + part[1][il][jl] +
                    part[2][il][jl] + part[3][il][jl] + base;
    out[(i0 + il) * NN + j0 + jl] = 1.f / (1.f + __expf(-x));
  }
}

extern "C" void kernel_launch(void* const* d_in, const int* in_sizes, int n_in,
                              void* d_out, int out_size, void* d_ws, size_t ws_size,
                              hipStream_t stream) {
  const float* z  = (const float*)d_in[0];
  const float* W1 = (const float*)d_in[1];
  const float* b1 = (const float*)d_in[2];
  const float* W2 = (const float*)d_in[3];
  const float* b2 = (const float*)d_in[4];
  float* out = (float*)d_out;
  char* ws = (char*)d_ws;

  k1_fused<<<dim3(64, 8), 256, 0, stream>>>(z, W1, b1, W2, ws);
  k2_pair<<<dim3(64, 16), 256, 0, stream>>>(
      (const float*)(ws + RF_OFF), (const float*)(ws + CF_OFF),
      W2, b2, out);
}